// Round 3
// baseline (103.151 us; speedup 1.0000x reference)
//
#include <hip/hip_runtime.h>

// HammingL2 on MI355X (gfx950), single fused kernel.
//
// out = (1/N) * sum_n [ d.v^2 - v^T W v ]          (d = rowsum W)
//     = (1/N) * <diag(d) - W, G>,   G = V^T V  (Gram, 256x256)
//     = (1/N) * sum_{r,c} W[r][c] * (G[r][r] - G[r][c])
//
// The last form needs neither d nor M = diag(d)-W: each block computes a
// Gram partial G_p over its 256 rows via mfma_f32_32x32x16_f16 (V cast to
// f16; W stays exact fp32), extracts diag(G_p) from the accumulators into
// LDS, and folds W * (diag - G_p) in the epilogue against L2-resident W.
// One scalar atomicAdd per block; d_out zeroed by a 4-byte memset node.

typedef _Float16 f16;
typedef _Float16 f16x8 __attribute__((ext_vector_type(8)));
typedef float f32x16 __attribute__((ext_vector_type(16)));

#define NLUT 65536
#define L 256
#define ROWS_PER_WG 256   // 4 chunks of 64 rows
#define NCHUNK 64

__global__ __launch_bounds__(512, 2) void hamming_fused(
    const float* __restrict__ V,   // [65536][256] fp32
    const float* __restrict__ W,   // [256][256] fp32 (symmetric, zero diag)
    float* __restrict__ out)
{
    // LDS: chunk of 64 V-rows, f16, transposed for MFMA frags.
    // Element (n, c) of chunk lives at [nblk=n>>3][c][n&7] -> the frag read
    // for col c, k-octet nblk is one contiguous, 16B-aligned f16x8.
    __shared__ f16 Vt[2][8][L][8];   // 2 x 32 KiB
    __shared__ float dgl[L];         // diag(G_p), 1 KiB
    __shared__ float red[8];
    const int tid  = threadIdx.x;
    const int lane = tid & 63;
    const int wv   = tid >> 6;        // 0..7
    const int h    = lane >> 5;       // k-half
    const int l31  = lane & 31;
    const int a    = wv >> 1;         // G rows [64a, 64a+64)
    const int b    = wv & 1;          // G cols [128b, 128b+128)
    const size_t n0 = (size_t)blockIdx.x * ROWS_PER_WG;

    f32x16 acc[2][4];
    #pragma unroll
    for (int x = 0; x < 2; ++x)
        #pragma unroll
        for (int y = 0; y < 4; ++y) acc[x][y] = (f32x16)(0.0f);

    float ld[4][8];

    // ---- prologue: stage chunk 0 (wave wv stages n-octet wv)
    {
        const float* src = V + (n0 + wv * 8) * L + lane;
        #pragma unroll
        for (int j = 0; j < 4; ++j)
            #pragma unroll
            for (int e = 0; e < 8; ++e)
                ld[j][e] = src[e * L + j * 64];     // coalesced: lanes = consecutive c
        #pragma unroll
        for (int j = 0; j < 4; ++j) {
            f16x8 p;
            #pragma unroll
            for (int e = 0; e < 8; ++e) p[e] = (f16)ld[j][e];
            *(f16x8*)&Vt[0][wv][lane + 64 * j][0] = p;  // contiguous b128 across wave
        }
    }
    __syncthreads();

    // ---- main loop: 4 chunks of 64 rows, double-buffered LDS
    for (int t = 0; t < 4; ++t) {
        if (t < 3) {   // issue next chunk's HBM loads before the MFMA phase
            const float* src = V + (n0 + (size_t)(t + 1) * NCHUNK + wv * 8) * L + lane;
            #pragma unroll
            for (int j = 0; j < 4; ++j)
                #pragma unroll
                for (int e = 0; e < 8; ++e)
                    ld[j][e] = src[e * L + j * 64];
        }

        const f16 (*buf)[L][8] = Vt[t & 1];
        #pragma unroll
        for (int ks = 0; ks < 4; ++ks) {
            // identical (lane,elem)->n map for A and B: any HW k-permutation cancels
            const f16 (*bk)[8] = buf[2 * ks + h];
            f16x8 fr[2], fc[4];
            fr[0] = *(const f16x8*)&bk[64 * a + l31][0];
            fr[1] = *(const f16x8*)&bk[64 * a + 32 + l31][0];
            #pragma unroll
            for (int y = 0; y < 4; ++y)
                fc[y] = *(const f16x8*)&bk[128 * b + 32 * y + l31][0];
            #pragma unroll
            for (int x = 0; x < 2; ++x)
                #pragma unroll
                for (int y = 0; y < 4; ++y)
                    acc[x][y] = __builtin_amdgcn_mfma_f32_32x32x16_f16(
                        fr[x], fc[y], acc[x][y], 0, 0, 0);
        }

        if (t < 3) {   // convert + write next chunk into the other buffer
            #pragma unroll
            for (int j = 0; j < 4; ++j) {
                f16x8 p;
                #pragma unroll
                for (int e = 0; e < 8; ++e) p[e] = (f16)ld[j][e];
                *(f16x8*)&Vt[(t + 1) & 1][wv][lane + 64 * j][0] = p;
            }
        }
        __syncthreads();
    }

    // ---- extract diag(G_p) into LDS (each c owned by exactly one thread/reg)
    // C/D map (verified m74/m101, dtype-independent):
    //   col = l31 (+tile col), row = (r&3) + 8*(r>>2) + 4*h (+tile row)
    #pragma unroll
    for (int x = 0; x < 2; ++x) {
        #pragma unroll
        for (int y = 0; y < 4; ++y) {
            const int col = 128 * b + 32 * y + l31;
            #pragma unroll
            for (int r = 0; r < 16; ++r) {
                const int row = 64 * a + 32 * x + 4 * h + (r & 3) + 8 * (r >> 2);
                if (row == col) dgl[row] = acc[x][y][r];
            }
        }
    }
    __syncthreads();

    // ---- epilogue: sloc = sum W[row][col] * (diag[row] - G_p[row][col])
    // W reads: fp32, consecutive cols across l31 -> coalesced, L2-resident.
    // dgl[row]: uniform per 32-lane half-group -> LDS broadcast, conflict-free.
    float sloc = 0.0f;
    #pragma unroll
    for (int x = 0; x < 2; ++x) {
        #pragma unroll
        for (int y = 0; y < 4; ++y) {
            const int col = 128 * b + 32 * y + l31;
            #pragma unroll
            for (int r = 0; r < 16; ++r) {
                const int row = 64 * a + 32 * x + 4 * h + (r & 3) + 8 * (r >> 2);
                sloc += W[row * L + col] * (dgl[row] - acc[x][y][r]);
            }
        }
    }
    #pragma unroll
    for (int off = 32; off; off >>= 1) sloc += __shfl_down(sloc, off, 64);

    if (lane == 0) red[wv] = sloc;
    __syncthreads();
    if (tid == 0) {
        float tot = 0.0f;
        #pragma unroll
        for (int i = 0; i < 8; ++i) tot += red[i];
        atomicAdd(out, tot * (1.0f / (float)NLUT));
    }
}

extern "C" void kernel_launch(void* const* d_in, const int* in_sizes, int n_in,
                              void* d_out, int out_size, void* d_ws, size_t ws_size,
                              hipStream_t stream) {
    const float* luts = (const float*)d_in[0];   // [65536*256] fp32
    const float* W    = (const float*)d_in[1];   // [256*256] fp32
    // d_in[2] = gamma: unused by the reference computation
    float* out = (float*)d_out;

    hipMemsetAsync(out, 0, sizeof(float), stream);   // capturable memset node
    hamming_fused<<<NLUT / ROWS_PER_WG, 512, 0, stream>>>(luts, W, out);
}